// Round 11
// baseline (160.471 us; speedup 1.0000x reference)
//
#include <hip/hip_runtime.h>
#include <hip/hip_bf16.h>
#include <math.h>

// ---------------------------------------------------------------------------
// AdderNet LeNet forward. R11: 6 -> 4 dispatches.
//  * BN stats via per-block SLOT STORES (no pre-zeroing needed -> prep
//    kernel deleted); consumers reduce the slots (adder2: slots1[720][40],
//    fc1: slots2[512][100]).
//  * w2t transpose folded into adder1 (blocks 0-124; consumed next dispatch).
//  * bn_pool_t deleted: adder2 epilogue pools PRE-BN via sign-aware minmax
//    (max over sc*v+bi = sc>0 ? sc*max+bi : sc*min+bi), writes packed
//    float2{max,min} in featT layout; fc1 applies BN2 affine+select on load.
//  * Pipeline: adder1(+w2t) -> adder2(BN1 finalize+pool-staged, minmax out)
//              -> fc1(BN2 finalize inline) -> fc2+softmax.
// ---------------------------------------------------------------------------

#define B_N 128
#define EPSBN 1e-5f

// ---- adder1 + BN1 slot partials + w2t fold ---------------------------------
// thread = (b,o,oh,owc in {0,1,2}) computing an 8-wide chunk of the ow row.
__global__ __launch_bounds__(256) void adder1_bn_kernel(
    const float* __restrict__ x, const float* __restrict__ w1,
    const float* __restrict__ w2,
    float* __restrict__ out, float* __restrict__ slots1,  // [720][40]
    float* __restrict__ w2t) {                            // [20][25][64]
  __shared__ float csum[40];
  const int tid = threadIdx.x;
  if (tid < 40) csum[tid] = 0.f;
  __syncthreads();
  int idx = blockIdx.x * 256 + tid;   // 184320 = 720*256
  int owc = idx % 3; int t = idx / 3;
  int oh  = t % 24;  t /= 24;
  int o   = t % 20;  int b = t / 20;
  const float* xb = x + b * 784;
  const float* wb = w1 + o * 25;
  float acc[8];
#pragma unroll
  for (int i = 0; i < 8; ++i) acc[i] = 0.f;
#pragma unroll
  for (int kh = 0; kh < 5; ++kh) {
    float xr[12];
    const float4* xp = (const float4*)(xb + (oh + kh) * 28 + owc * 8);
#pragma unroll
    for (int i = 0; i < 3; ++i) {
      float4 v = xp[i];
      xr[4*i] = v.x; xr[4*i+1] = v.y; xr[4*i+2] = v.z; xr[4*i+3] = v.w;
    }
    float wr[5];
#pragma unroll
    for (int i = 0; i < 5; ++i) wr[i] = wb[kh * 5 + i];
#pragma unroll
    for (int ow = 0; ow < 8; ++ow)
#pragma unroll
      for (int kw = 0; kw < 5; ++kw)
        acc[ow] += fabsf(xr[ow + kw] - wr[kw]);
  }
  float* op = out + (((size_t)b * 20 + o) * 24 + oh) * 24 + owc * 8;
  float4 s0 = { -acc[0], -acc[1], -acc[2], -acc[3] };
  float4 s1 = { -acc[4], -acc[5], -acc[6], -acc[7] };
  *(float4*)(op)     = s0;
  *(float4*)(op + 4) = s1;
  float s = 0.f, s2 = 0.f;
#pragma unroll
  for (int i = 0; i < 8; ++i) { s -= acc[i]; s2 += acc[i] * acc[i]; }
  atomicAdd(&csum[o * 2],     s);
  atomicAdd(&csum[o * 2 + 1], s2);
  __syncthreads();
  if (tid < 40) slots1[blockIdx.x * 40 + tid] = csum[tid];  // plain store

  // w2t fold: blocks 0-124 transpose w2[50,20,5,5] -> w2t[c][k][o(64)]
  if (blockIdx.x < 125) {
    int i = blockIdx.x * 256 + tid;   // < 32000
    int oo = i & 63, tt = i >> 6, k = tt % 25, c = tt / 25;
    w2t[i] = (oo < 50) ? w2[oo * 500 + c * 25 + k] : 0.f;
  }
}

// ---- adder2: BN1 finalize (slot reduce) + pooled LDS staging + compute -----
// + minmax pool epilogue (featMM float2{max,min}, featT layout) + BN2 slots.
__global__ __launch_bounds__(256) void adder2_bn_kernel(
    const float* __restrict__ h1, const float* __restrict__ slots1,
    const float* __restrict__ g1, const float* __restrict__ be1,
    const float* __restrict__ w2t,
    float2* __restrict__ featMM,        // [800][128] of {max,min}
    float* __restrict__ slots2) {       // [512][100]
  __shared__ float lh[1440];    // [c][6 rows][12]
  __shared__ float sbb[40];     // BN1 (scale,bias)
  __shared__ float red[240];
  __shared__ float csum[100];
  const int tid = threadIdx.x;
  if (tid < 100) csum[tid] = 0.f;

  // BN1 finalize: reduce slots1[720][40]
  if (tid < 240) {
    int e = tid % 40, seg = tid / 40;           // 6 segs x 120 slots
    float r = 0.f;
    const float* sp = slots1 + (seg * 120) * 40 + e;
    for (int i = 0; i < 120; ++i) r += sp[i * 40];
    red[tid] = r;
  }
  __syncthreads();
  if (tid < 20) {
    float sm = 0.f, s2 = 0.f;
#pragma unroll
    for (int sgi = 0; sgi < 6; ++sgi) {
      sm += red[sgi * 40 + 2 * tid];
      s2 += red[sgi * 40 + 2 * tid + 1];
    }
    const float inv_n = 1.f / (B_N * 576);
    float mean = sm * inv_n;
    float var  = s2 * inv_n - mean * mean;
    float sc   = g1[tid] * rsqrtf(var + EPSBN);
    sbb[2 * tid]     = sc;
    sbb[2 * tid + 1] = be1[tid] - mean * sc;
  }
  __syncthreads();

  const int oq = blockIdx.x & 3;
  const int b  = blockIdx.x >> 2;   // 512 blocks = 128 b * 4 oq

  // stage: lh[c][r][col] = BN1+pool of h1[b][c][4oq+2r ..+1][2col ..+1]
  {
    const float* hb = h1 + (size_t)b * 11520;   // 20*24*24
    for (int j = tid; j < 1440; j += 256) {
      int c = j / 72, rem = j - c * 72;
      int r = rem / 12, col = rem - r * 12;
      const float* hp = hb + (c * 24 + (4 * oq + 2 * r)) * 24 + 2 * col;
      float2 r0 = *(const float2*)(hp);
      float2 r1 = *(const float2*)(hp + 24);
      float sc = sbb[2 * c], bi = sbb[2 * c + 1];
      float v0 = fmaf(sc, r0.x, bi);
      float v1 = fmaf(sc, r0.y, bi);
      float v2 = fmaf(sc, r1.x, bi);
      float v3 = fmaf(sc, r1.y, bi);
      lh[j] = fmaxf(fmaxf(v0, v1), fmaxf(v2, v3));
    }
  }
  __syncthreads();

  const int o   = tid >> 2;           // 0..63 (active < 50)
  const int q   = tid & 3;
  const int ohl = q >> 1;             // local oh (row 2oq+ohl)
  const int owh = q & 1;              // ow half (cols owh*4..+3)
  if (o < 50) {
    float acc[4];
#pragma unroll
    for (int i = 0; i < 4; ++i) acc[i] = 0.f;
    for (int c = 0; c < 20; ++c) {
      const float* lc = lh + c * 72 + owh * 4;
      const float* wc = w2t + c * 1600 + o;
#pragma unroll
      for (int kh = 0; kh < 5; ++kh) {
        float hr[8];
        const float* lp = lc + (ohl + kh) * 12;
        *(float4*)(hr)     = *(const float4*)(lp);
        *(float4*)(hr + 4) = *(const float4*)(lp + 4);
        float wr[5];
#pragma unroll
        for (int i = 0; i < 5; ++i) wr[i] = wc[(kh * 5 + i) * 64];
#pragma unroll
        for (int ow = 0; ow < 4; ++ow)
#pragma unroll
          for (int kw = 0; kw < 5; ++kw)
            acc[ow] += fabsf(hr[ow + kw] - wr[kw]);
      }
    }
    // raw h2 values
    float v0 = -acc[0], v1 = -acc[1], v2 = -acc[2], v3 = -acc[3];
    // BN2 partials from raw values
    float s  = v0 + v1 + v2 + v3;
    float s2 = v0*v0 + v1*v1 + v2*v2 + v3*v3;
    atomicAdd(&csum[o * 2],     s);
    atomicAdd(&csum[o * 2 + 1], s2);
    // 2x2 minmax pool: pairs within thread (ow), partner across ohl (tid^2)
    float pM0 = fmaxf(v0, v1), pM1 = fmaxf(v2, v3);
    float pm0 = fminf(v0, v1), pm1 = fminf(v2, v3);
    float qM0 = fmaxf(pM0, __shfl_xor(pM0, 2));
    float qM1 = fmaxf(pM1, __shfl_xor(pM1, 2));
    float qm0 = fminf(pm0, __shfl_xor(pm0, 2));
    float qm1 = fminf(pm1, __shfl_xor(pm1, 2));
    if (ohl == 0) {
      int k0 = o * 16 + oq * 4 + owh * 2;   // featT index k = c*16+ph*4+pw
      featMM[(size_t)k0 * 128 + b]       = make_float2(qM0, qm0);
      featMM[(size_t)(k0 + 1) * 128 + b] = make_float2(qM1, qm1);
    }
  }
  __syncthreads();
  if (tid < 100) slots2[blockIdx.x * 100 + tid] = csum[tid];  // plain store
}

// ---- fc1 + relu, BN2 finalize inline: featMM -> hid[128][512] --------------
// block = j (500); 256 thr = 128 b x 2 k-halves; feat = BN2-select of minmax.
__global__ __launch_bounds__(256) void fc1_kernel(
    const float2* __restrict__ featMM, const float* __restrict__ slots2,
    const float* __restrict__ g2, const float* __restrict__ be2,
    const float* __restrict__ w1, const float* __restrict__ b1,
    float* __restrict__ hid) {
  __shared__ float sb2[100];    // BN2 (scale,bias)
  __shared__ float red2[200];
  __shared__ float part[256];
  const int tid = threadIdx.x;
  // BN2 finalize: reduce slots2[512][100]
  if (tid < 200) {
    int e = tid % 100, h = tid / 100;          // 2 halves x 256 slots
    float r = 0.f;
    const float* sp = slots2 + (h * 256) * 100 + e;
    for (int i = 0; i < 256; ++i) r += sp[i * 100];
    red2[tid] = r;
  }
  __syncthreads();
  if (tid < 50) {
    float sm = red2[2 * tid]     + red2[100 + 2 * tid];
    float s2 = red2[2 * tid + 1] + red2[100 + 2 * tid + 1];
    const float inv_n = 1.f / (B_N * 64);
    float mean = sm * inv_n;
    float var  = s2 * inv_n - mean * mean;
    float sc   = g2[tid] * rsqrtf(var + EPSBN);
    sb2[2 * tid]     = sc;
    sb2[2 * tid + 1] = be2[tid] - mean * sc;
  }
  __syncthreads();

  const int j = blockIdx.x;
  const int b = tid & 127;
  const int khalf = tid >> 7;
  const float* wr = w1 + j * 800;
  float a0 = 0.f, a1 = 0.f, a2 = 0.f, a3 = 0.f;
  // 25 groups of 16 k (one channel per group): kg in [khalf*25, khalf*25+25)
  for (int kg = khalf * 25; kg < khalf * 25 + 25; ++kg) {
    float sc = sb2[2 * kg], bi = sb2[2 * kg + 1];   // c == kg (k = c*16+r)
    int kbase = kg * 16;
#pragma unroll
    for (int r = 0; r < 16; r += 4) {
      float4 w4 = *(const float4*)(wr + kbase + r);   // wave-uniform
      float2 f0 = featMM[(size_t)(kbase + r    ) * 128 + b];
      float2 f1 = featMM[(size_t)(kbase + r + 1) * 128 + b];
      float2 f2 = featMM[(size_t)(kbase + r + 2) * 128 + b];
      float2 f3 = featMM[(size_t)(kbase + r + 3) * 128 + b];
      float e0 = fmaf(sc, sc > 0.f ? f0.x : f0.y, bi);
      float e1 = fmaf(sc, sc > 0.f ? f1.x : f1.y, bi);
      float e2 = fmaf(sc, sc > 0.f ? f2.x : f2.y, bi);
      float e3 = fmaf(sc, sc > 0.f ? f3.x : f3.y, bi);
      a0 = fmaf(e0, w4.x, a0);
      a1 = fmaf(e1, w4.y, a1);
      a2 = fmaf(e2, w4.z, a2);
      a3 = fmaf(e3, w4.w, a3);
    }
  }
  part[tid] = (a0 + a1) + (a2 + a3);
  __syncthreads();
  if (tid < 128)
    hid[b * 512 + j] = fmaxf(b1[j] + part[tid] + part[tid + 128], 0.f);
}

// ---- fc2 + bias + softmax: hid[128][512] x w[10,500] -> out[128][10] -------
__global__ __launch_bounds__(64) void fc2_softmax_kernel(
    const float* __restrict__ hid, const float* __restrict__ w2,
    const float* __restrict__ b2, float* __restrict__ out) {
  const int b = blockIdx.x, lane = threadIdx.x;
  const float* hb = hid + b * 512;
  __shared__ float logit[16];
  float hv[8];
#pragma unroll
  for (int i = 0; i < 8; ++i) {
    int k = lane + 64 * i;
    hv[i] = (k < 500) ? hb[k] : 0.f;
  }
  for (int j = 0; j < 10; ++j) {
    const float* wr = w2 + j * 500;
    float acc = 0.f;
#pragma unroll
    for (int i = 0; i < 8; ++i) {
      int k = lane + 64 * i;
      float w = (k < 500) ? wr[k] : 0.f;
      acc = fmaf(hv[i], w, acc);
    }
#pragma unroll
    for (int off = 32; off > 0; off >>= 1) acc += __shfl_down(acc, off);
    if (lane == 0) logit[j] = acc + b2[j];
  }
  __syncthreads();
  if (lane == 0) {
    float m = logit[0];
    for (int j = 1; j < 10; ++j) m = fmaxf(m, logit[j]);
    float s = 0.f, e[10];
    for (int j = 0; j < 10; ++j) { e[j] = __expf(logit[j] - m); s += e[j]; }
    float inv = 1.f / s;
    for (int j = 0; j < 10; ++j) out[b * 10 + j] = e[j] * inv;
  }
}

extern "C" void kernel_launch(void* const* d_in, const int* in_sizes, int n_in,
                              void* d_out, int out_size, void* d_ws, size_t ws_size,
                              hipStream_t stream) {
  const float* x   = (const float*)d_in[0];   // [128,1,28,28]
  const float* w1  = (const float*)d_in[1];   // [20,1,5,5]
  const float* g1  = (const float*)d_in[2];   // [20]
  const float* be1 = (const float*)d_in[3];   // [20]
  const float* w2  = (const float*)d_in[4];   // [50,20,5,5]
  const float* g2  = (const float*)d_in[5];   // [50]
  const float* be2 = (const float*)d_in[6];   // [50]
  const float* fw1 = (const float*)d_in[7];   // [500,800]
  const float* fb1 = (const float*)d_in[8];   // [500]
  const float* fw2 = (const float*)d_in[9];   // [10,500]
  const float* fb2 = (const float*)d_in[10];  // [10]
  float* out = (float*)d_out;

  // workspace layout (floats) — all disjoint, nothing needs pre-zeroing
  // (slot arrays fully overwritten each call; featMM/hid fully written).
  float*  ws     = (float*)d_ws;
  float*  h1     = ws;               // [0, 1474560)       128*20*24*24
  float*  slots1 = ws + 1843200;     // 720*40  = 28800
  float*  slots2 = ws + 1872128;     // 512*100 = 51200
  float*  w2t    = ws + 1923584;     // 32000
  float2* featMM = (float2*)(ws + 1956000); // 800*128 float2 = 204800 floats
  float*  hid    = ws + 2170000;     // 128*512

  adder1_bn_kernel<<<720, 256, 0, stream>>>(x, w1, w2, h1, slots1, w2t);
  adder2_bn_kernel<<<512, 256, 0, stream>>>(h1, slots1, g1, be1, w2t,
                                            featMM, slots2);
  fc1_kernel<<<500, 256, 0, stream>>>(featMM, slots2, g2, be2, fw1, fb1, hid);
  fc2_softmax_kernel<<<128, 64, 0, stream>>>(hid, fw2, fb2, out);
}